// Round 4
// baseline (63.197 us; speedup 1.0000x reference)
//
#include <hip/hip_runtime.h>

#define TWO_N 8192
#define HALF_N 4096
#define DIM 256

#define ROWS_PER_WAVE 32
#define ROWS_PER_BLOCK 128
#define ROWBLOCKS (TWO_N / ROWS_PER_BLOCK)   // 64
#define COLSPLIT 16
#define COLS_PER_BLOCK (TWO_N / COLSPLIT)    // 512
#define CH_COLS 32
#define CHUNK_BYTES (CH_COLS * DIM * 2)      // 16 KB
#define NCHUNK (COLS_PER_BLOCK / CH_COLS)    // 16

#define KAPPA 14.426950408889634f            // 10*log2(e)
#define LN2 0.6931471805599453f

typedef __attribute__((ext_vector_type(8))) short bf16x8;
typedef __attribute__((ext_vector_type(4))) float f32x4;

__device__ __forceinline__ float bf2f(unsigned short u) {
  return __uint_as_float(((unsigned int)u) << 16);
}
__device__ __forceinline__ unsigned short f2bf(float f) {
  unsigned int u = __float_as_uint(f);
  return (unsigned short)((u + 0x7FFFu + ((u >> 16) & 1u)) >> 16);
}
__device__ __forceinline__ void async_copy16(void* lds_dst, const void* g_src) {
  __builtin_amdgcn_global_load_lds(
      (const __attribute__((address_space(1))) unsigned int*)g_src,
      (__attribute__((address_space(3))) unsigned int*)lds_dst, 16, 0, 0);
}

// K1: L2-normalize rows of [z_i; z_j]. rn = bf16(r), rnA = bf16(KAPPA*r).
// Also zero rowsum and out.
__global__ __launch_bounds__(256) void k_norm(const float* __restrict__ zi,
                                              const float* __restrict__ zj,
                                              unsigned short* __restrict__ rn,
                                              unsigned short* __restrict__ rnA,
                                              float* __restrict__ rowsum,
                                              float* __restrict__ out) {
  int wave = threadIdx.x >> 6, lane = threadIdx.x & 63;
  int row = blockIdx.x * 4 + wave;
  if (threadIdx.x < 4) rowsum[blockIdx.x * 4 + threadIdx.x] = 0.0f;
  if (blockIdx.x == 0 && threadIdx.x == 0) out[0] = 0.0f;
  const float* src = (row < HALF_N) ? (zi + (size_t)row * DIM)
                                    : (zj + (size_t)(row - HALF_N) * DIM);
  float4 v = *reinterpret_cast<const float4*>(src + lane * 4);
  float ss = v.x * v.x + v.y * v.y + v.z * v.z + v.w * v.w;
  #pragma unroll
  for (int m = 32; m >= 1; m >>= 1) ss += __shfl_xor(ss, m, 64);
  float r = rsqrtf(ss);
  ushort4 o;
  o.x = f2bf(v.x * r); o.y = f2bf(v.y * r);
  o.z = f2bf(v.z * r); o.w = f2bf(v.w * r);
  *reinterpret_cast<ushort4*>(rn + (size_t)row * DIM + lane * 4) = o;
  float rk = r * KAPPA;
  ushort4 oa;
  oa.x = f2bf(v.x * rk); oa.y = f2bf(v.y * rk);
  oa.z = f2bf(v.z * rk); oa.w = f2bf(v.w * rk);
  *reinterpret_cast<ushort4*>(rnA + (size_t)row * DIM + lane * 4) = oa;
}

// K2: Gram via MFMA. B panels staged into LDS in FRAGMENT-MAJOR order:
// slot (half h, kk, lane) at h*8192 + kk*1024 + lane*16 holds
// rn[col = h*16 + (lane&15)][k bytes kk*64 + (lane>>4)*16 .. +16].
// Consuming ds_read_b128 is perfectly linear per wave (conflict-free) with
// immediate offsets. A is pre-scaled by KAPPA and acc inits at -KAPPA, so the
// epilogue is exp2(acc) + add only. Diagonal left in; removed in K3.
__global__ __launch_bounds__(256, 4) void k_sim(const unsigned short* __restrict__ rn,
                                                const unsigned short* __restrict__ rnA,
                                                float* __restrict__ rowsum) {
  __shared__ alignas(16) char lds[2][CHUNK_BYTES];
  int cs = blockIdx.x & (COLSPLIT - 1);       // low bits -> XCD affinity
  int rb = blockIdx.x >> 4;
  int wave = threadIdx.x >> 6, lane = threadIdx.x & 63;
  int lrow = lane & 15, kgrp = lane >> 4;
  int r0 = rb * ROWS_PER_BLOCK + wave * ROWS_PER_WAVE;
  const int cbase = cs * COLS_PER_BLOCK;

  // A fragments: two 16-row strips of rnA, resident in VGPRs (64 regs).
  bf16x8 a[2][8];
  #pragma unroll
  for (int s = 0; s < 2; ++s) {
    const unsigned short* p = rnA + (size_t)(r0 + 16 * s + lrow) * DIM + kgrp * 8;
    #pragma unroll
    for (int kk = 0; kk < 8; ++kk)
      a[s][kk] = *reinterpret_cast<const bf16x8*>(p + kk * 32);
  }

  float se[2][4];
  #pragma unroll
  for (int s = 0; s < 2; ++s)
    #pragma unroll
    for (int g = 0; g < 4; ++g) se[s][g] = 0.0f;

  // Staging: 16 x 1KB slices per chunk; wave w covers h = w>>1, kk = (w&1)*4+t.
  int sh = wave >> 1;
  int sk0 = (wave & 1) * 4;
  auto stage = [&](int buf, int ch) {
    const char* gb = (const char*)rn +
        (size_t)(cbase + ch * CH_COLS + sh * 16 + lrow) * 512 + kgrp * 16;
    char* db = &lds[buf][sh * 8192 + sk0 * 1024];
    #pragma unroll
    for (int t = 0; t < 4; ++t)
      async_copy16(db + t * 1024, gb + (sk0 + t) * 64);
  };

  stage(0, 0);
  __syncthreads();

  for (int ch = 0; ch < NCHUNK; ++ch) {
    if (ch + 1 < NCHUNK) stage((ch + 1) & 1, ch + 1);
    const char* lb = lds[ch & 1] + lane * 16;
    #pragma unroll
    for (int h = 0; h < 2; ++h) {
      f32x4 acc0 = {-KAPPA, -KAPPA, -KAPPA, -KAPPA};
      f32x4 acc1 = {-KAPPA, -KAPPA, -KAPPA, -KAPPA};
      #pragma unroll
      for (int kk = 0; kk < 8; ++kk) {
        bf16x8 b = *reinterpret_cast<const bf16x8*>(lb + h * 8192 + kk * 1024);
        acc0 = __builtin_amdgcn_mfma_f32_16x16x32_bf16(a[0][kk], b, acc0, 0, 0, 0);
        acc1 = __builtin_amdgcn_mfma_f32_16x16x32_bf16(a[1][kk], b, acc1, 0, 0, 0);
      }
      #pragma unroll
      for (int g = 0; g < 4; ++g) {
        se[0][g] += __builtin_amdgcn_exp2f(acc0[g]);
        se[1][g] += __builtin_amdgcn_exp2f(acc1[g]);
      }
    }
    __syncthreads();   // stage(ch+1) drained; buf swap safe
  }

  // reduce over the 16 column-lanes, then one atomic per row
  #pragma unroll
  for (int s = 0; s < 2; ++s) {
    #pragma unroll
    for (int g = 0; g < 4; ++g) {
      float v = se[s][g];
      #pragma unroll
      for (int m = 1; m <= 8; m <<= 1) v += __shfl_xor(v, m, 64);
      if (lrow == 0) atomicAdd(&rowsum[r0 + 16 * s + kgrp * 4 + g], v);
    }
  }
}

// K3: per-row: subtract self term, lse - pos, mean via atomics.
// dots = KAPPA*d_ii, dotp = KAPPA*d_ij (A-scaled dots, matching K2's products).
__global__ __launch_bounds__(256) void k_rowred(const unsigned short* __restrict__ rn,
                                               const unsigned short* __restrict__ rnA,
                                               const float* __restrict__ rowsum,
                                               float* __restrict__ out) {
  __shared__ float ls[4];
  int wave = threadIdx.x >> 6, lane = threadIdx.x & 63;
  float local = 0.0f;
  #pragma unroll
  for (int t = 0; t < 8; ++t) {
    int i = blockIdx.x * 32 + wave * 8 + t;
    int j = (i + HALF_N) & (TWO_N - 1);
    ushort4 ai = *reinterpret_cast<const ushort4*>(rnA + (size_t)i * DIM + lane * 4);
    ushort4 bi = *reinterpret_cast<const ushort4*>(rn + (size_t)i * DIM + lane * 4);
    ushort4 bj = *reinterpret_cast<const ushort4*>(rn + (size_t)j * DIM + lane * 4);
    float ax = bf2f(ai.x), ay = bf2f(ai.y), az = bf2f(ai.z), aw = bf2f(ai.w);
    float dots = ax * bf2f(bi.x) + ay * bf2f(bi.y) + az * bf2f(bi.z) + aw * bf2f(bi.w);
    float dotp = ax * bf2f(bj.x) + ay * bf2f(bj.y) + az * bf2f(bj.z) + aw * bf2f(bj.w);
    #pragma unroll
    for (int m = 32; m >= 1; m >>= 1) {
      dots += __shfl_xor(dots, m, 64);
      dotp += __shfl_xor(dotp, m, 64);
    }
    if (lane == 0) {
      float self = __builtin_amdgcn_exp2f(dots - KAPPA);
      float rs = rowsum[i] - self;
      float lse = 10.0f + LN2 * __builtin_amdgcn_logf(rs);  // logf = log2
      local += lse - LN2 * dotp;                            // pos = ln2*KAPPA*d = 10*d
    }
  }
  if (lane == 0) ls[wave] = local;
  __syncthreads();
  if (threadIdx.x == 0) {
    float t = (ls[0] + ls[1] + ls[2] + ls[3]) * (1.0f / TWO_N);
    atomicAdd(out, t);
  }
}

extern "C" void kernel_launch(void* const* d_in, const int* in_sizes, int n_in,
                              void* d_out, int out_size, void* d_ws, size_t ws_size,
                              hipStream_t stream) {
  const float* zi = (const float*)d_in[0];
  const float* zj = (const float*)d_in[1];
  unsigned short* rn = (unsigned short*)d_ws;                        // 4 MB
  unsigned short* rnA = rn + (size_t)TWO_N * DIM;                    // 4 MB
  float* rowsum = (float*)((char*)d_ws + (size_t)TWO_N * DIM * 4);   // 32 KB
  float* out = (float*)d_out;

  hipLaunchKernelGGL(k_norm, dim3(TWO_N / 4), dim3(256), 0, stream, zi, zj, rn, rnA, rowsum, out);
  hipLaunchKernelGGL(k_sim, dim3(ROWBLOCKS * COLSPLIT), dim3(256), 0, stream, rn, rnA, rowsum);
  hipLaunchKernelGGL(k_rowred, dim3(TWO_N / 32), dim3(256), 0, stream, rn, rnA, rowsum, out);
}